// Round 10
// baseline (507.048 us; speedup 1.0000x reference)
//
#include <hip/hip_runtime.h>
#include <math.h>

#define BB   2
#define SEQ  4096
#define DIM  512
#define NH   8
#define HD   64
#define MLPD 2048
#define ROWS (BB*SEQ)          /* 8192 */
#define SZ   (ROWS*DIM)        /* 4194304 elements */
#define EPSV 1e-5f

typedef __attribute__((ext_vector_type(8))) short bf16x8;   // A/B frag: 8 bf16
typedef __attribute__((ext_vector_type(4))) float f32x4;    // C/D frag: 4 f32

#if __has_builtin(__builtin_amdgcn_exp2f)
#define EXP2(x) __builtin_amdgcn_exp2f(x)
#else
#define EXP2(x) exp2f(x)
#endif

__device__ __forceinline__ ushort f2bf(float f) {           // RNE float->bf16
    unsigned u = __float_as_uint(f);
    u += 0x7fffu + ((u >> 16) & 1u);
    return (ushort)(u >> 16);
}
__device__ __forceinline__ unsigned pack2bf(float a, float b) {  // [b:a] packed
    return (unsigned)f2bf(a) | ((unsigned)f2bf(b) << 16);
}

__device__ __forceinline__ void gload16(const ushort* g, ushort* l) {
    __builtin_amdgcn_global_load_lds(
        (const __attribute__((address_space(1))) unsigned*)g,
        (__attribute__((address_space(3))) unsigned*)l, 16, 0, 0);
}

// ---------------- LayerNorm -> bf16 (one block = one row of 512) ----------------
__global__ __launch_bounds__(128) void ln_kernel(const float* __restrict__ x,
        const float* __restrict__ g, const float* __restrict__ be,
        ushort* __restrict__ out)
{
    int row = blockIdx.x;
    int tid = threadIdx.x;
    const float4 v = ((const float4*)(x + (size_t)row*DIM))[tid];
    float s  = v.x + v.y + v.z + v.w;
    float ss = v.x*v.x + v.y*v.y + v.z*v.z + v.w*v.w;
    #pragma unroll
    for (int off = 32; off > 0; off >>= 1) {
        s  += __shfl_down(s,  off);
        ss += __shfl_down(ss, off);
    }
    __shared__ float red[4];
    if ((tid & 63) == 0) { red[(tid>>6)*2+0] = s; red[(tid>>6)*2+1] = ss; }
    __syncthreads();
    float sum = red[0] + red[2], sumsq = red[1] + red[3];
    float mu  = sum * (1.0f/DIM);
    float var = sumsq * (1.0f/DIM) - mu*mu;
    float rs  = rsqrtf(var + EPSV);
    float4 gv = ((const float4*)g)[tid];
    float4 bv = ((const float4*)be)[tid];
    ushort4 o;
    o.x = f2bf((v.x - mu)*rs*gv.x + bv.x);
    o.y = f2bf((v.y - mu)*rs*gv.y + bv.y);
    o.z = f2bf((v.z - mu)*rs*gv.z + bv.z);
    o.w = f2bf((v.w - mu)*rs*gv.w + bv.w);
    ((ushort4*)(out + (size_t)row*DIM))[tid] = o;
}

// ---------------- Weight transpose-convert: fp32 [K][N] -> bf16 [N][K] ----------------
__global__ __launch_bounds__(256) void wtrans_kernel(const float* __restrict__ W,
        ushort* __restrict__ Wt, int K, int N)
{
    __shared__ ushort T[64][65];
    int n0 = blockIdx.x*64, k0 = blockIdx.y*64;
    int tid = threadIdx.x;
    #pragma unroll
    for (int p = 0; p < 4; ++p) {
        int r = p*16 + (tid>>4), c = (tid&15)<<2;
        float4 w4 = *(const float4*)(W + (size_t)(k0+r)*N + n0 + c);
        T[c+0][r] = f2bf(w4.x); T[c+1][r] = f2bf(w4.y);
        T[c+2][r] = f2bf(w4.z); T[c+3][r] = f2bf(w4.w);
    }
    __syncthreads();
    #pragma unroll
    for (int p = 0; p < 4; ++p) {
        int n = p*16 + (tid>>4), k = (tid&15)<<2;
        ushort4 o; o.x = T[n][k]; o.y = T[n][k+1]; o.z = T[n][k+2]; o.w = T[n][k+3];
        *(ushort4*)(Wt + (size_t)(n0+n)*K + k0 + k) = o;
    }
}

// 4x 512x512 weights in one launch (z selects)
__global__ __launch_bounds__(256) void wtrans4_kernel(
        const float* __restrict__ W0, const float* __restrict__ W1,
        const float* __restrict__ W2, const float* __restrict__ W3,
        ushort* __restrict__ Wt)
{
    __shared__ ushort T[64][65];
    int z = blockIdx.z;
    const float* W = (z==0) ? W0 : (z==1) ? W1 : (z==2) ? W2 : W3;
    ushort* Wtz = Wt + (size_t)z*512*512;
    int n0 = blockIdx.x*64, k0 = blockIdx.y*64;
    int tid = threadIdx.x;
    #pragma unroll
    for (int p = 0; p < 4; ++p) {
        int r = p*16 + (tid>>4), c = (tid&15)<<2;
        float4 w4 = *(const float4*)(W + (size_t)(k0+r)*512 + n0 + c);
        T[c+0][r] = f2bf(w4.x); T[c+1][r] = f2bf(w4.y);
        T[c+2][r] = f2bf(w4.z); T[c+3][r] = f2bf(w4.w);
    }
    __syncthreads();
    #pragma unroll
    for (int p = 0; p < 4; ++p) {
        int n = p*16 + (tid>>4), k = (tid&15)<<2;
        ushort4 o; o.x = T[n][k]; o.y = T[n][k+1]; o.z = T[n][k+2]; o.w = T[n][k+3];
        *(ushort4*)(Wtz + (size_t)(n0+n)*512 + k0 + k) = o;
    }
}

// ---------------- bf16 MFMA GEMM, BN=64, BK=32, double-buffered (R8-proven) ----------------
// flags: 1=QKV-split 2=GELU 4=+resid 8=+bias 16=bf16 out
template<int BM, int NT>
__global__ __launch_bounds__(NT) void gemm_bf16_kernel(
        const ushort* __restrict__ A,
        const ushort* __restrict__ Wta, const ushort* __restrict__ Wtb, const ushort* __restrict__ Wtc,
        const float* __restrict__ bias, const float* __restrict__ resid,
        void* __restrict__ outv, int M, int Nn, int K, int flags)
{
    constexpr int AISS = (BM*4)/NT;      // A-tile DMA issues
    constexpr int BISS = 256/NT;         // B-tile DMA issues
    __shared__ ushort As[2][BM*32];
    __shared__ ushort Bs[2][64*32];
    int tid = threadIdx.x;
    int w = tid >> 6, lane = tid & 63, quad = lane >> 4, col = lane & 15;
    int row0 = blockIdx.y * BM, col0 = blockIdx.x * 64;
    int wm0 = w * 32;

    const ushort* Wt; int wcol0, ostride, obase_col;
    float qscale = 1.0f;
    float* outF = nullptr; ushort* outB = nullptr;
    if (flags & 1) {
        int sel = col0 >> 9;
        Wt = (sel == 0) ? Wta : ((sel == 1) ? Wtb : Wtc);
        wcol0 = col0 & 511; ostride = 512; obase_col = wcol0;
        outB = (ushort*)outv + (size_t)sel * ((size_t)M * 512);
        if (sel == 0) qscale = 0.125f * 1.44269504088896f;  // 1/sqrt(HD) * log2(e)
        flags |= 16;
    } else {
        Wt = Wta; wcol0 = col0; ostride = Nn; obase_col = col0;
        if (flags & 16) outB = (ushort*)outv; else outF = (float*)outv;
    }

    f32x4 acc[2][4];
    #pragma unroll
    for (int i = 0; i < 2; ++i)
        #pragma unroll
        for (int j = 0; j < 4; ++j) acc[i][j] = (f32x4){0.f,0.f,0.f,0.f};

    const ushort* Ag = A  + (size_t)(row0  + (tid >> 2))*K + ((tid & 3) << 3);
    const ushort* Bg = Wt + (size_t)(wcol0 + (tid >> 2))*K + ((tid & 3) << 3);

    auto issue = [&](ushort* Ad, ushort* Bd, int ko) {
        #pragma unroll
        for (int it = 0; it < AISS; ++it)
            gload16(Ag + ko + (size_t)(it*(NT/4))*K, Ad + it*NT*8 + tid*8);
        #pragma unroll
        for (int it = 0; it < BISS; ++it)
            gload16(Bg + ko + (size_t)(it*(NT/4))*K, Bd + it*NT*8 + tid*8);
    };
    auto compute = [&](const ushort* Ab, const ushort* Bb) {
        bf16x8 af[2], bfr[4];
        #pragma unroll
        for (int i = 0; i < 2; ++i)
            af[i] = *(const bf16x8*)(Ab + (wm0 + i*16 + col)*32 + quad*8);
        #pragma unroll
        for (int j = 0; j < 4; ++j)
            bfr[j] = *(const bf16x8*)(Bb + (j*16 + col)*32 + quad*8);
        #pragma unroll
        for (int i = 0; i < 2; ++i)
            #pragma unroll
            for (int j = 0; j < 4; ++j)
                acc[i][j] = __builtin_amdgcn_mfma_f32_16x16x32_bf16(af[i], bfr[j], acc[i][j], 0, 0, 0);
    };

    int niter = K >> 5;                 // K/32, always even here
    issue(As[0], Bs[0], 0);
    for (int i = 0; i < niter; i += 2) {
        __syncthreads();                              // publish buf0 (DMA drained)
        if (i + 1 < niter) issue(As[1], Bs[1], (i+1)*32);   // prefetch overlaps compute
        compute(As[0], Bs[0]);
        __syncthreads();                              // publish buf1
        if (i + 2 < niter) issue(As[0], Bs[0], (i+2)*32);
        compute(As[1], Bs[1]);
    }

    #pragma unroll
    for (int i = 0; i < 2; ++i) {
        #pragma unroll
        for (int r = 0; r < 4; ++r) {
            int row = row0 + wm0 + i*16 + quad*4 + r;
            #pragma unroll
            for (int j = 0; j < 4; ++j) {
                int oc = obase_col + j*16 + col;
                float o = acc[i][j][r] * qscale;
                if (flags & 8) o += bias[oc];
                if (flags & 2) o = 0.5f*o*(1.f + erff(o*0.70710678118654752f));
                if (flags & 4) o += resid[(size_t)row*ostride + oc];
                if (flags & 16) outB[(size_t)row*ostride + oc] = f2bf(o);
                else            outF[(size_t)row*ostride + oc] = o;
            }
        }
    }
}

// ---------------- V transpose with key permutation ----------------
// v[b,n,h*64+d] -> vt[bh][d][tile*64 + key'] where key' = (k&15)*4 + (k>>4).
__global__ __launch_bounds__(256) void vtrans_kernel(const ushort* __restrict__ v,
                                                     ushort* __restrict__ vt)
{
    int tt = blockIdx.x, bh = blockIdx.y;
    int b = bh >> 3, h = bh & 7;
    int tid = threadIdx.x;
    int d = tid >> 2, t0 = (tid & 3) << 4;     // 16 consecutive key' per thread
    ushort tmp[16];
    #pragma unroll
    for (int i = 0; i < 16; ++i) {
        int korig = (i & 3)*16 + ((tid & 3) << 2) + (i >> 2);   // inverse perm
        tmp[i] = v[(size_t)(b*SEQ + tt*64 + korig)*DIM + h*HD + d];
    }
    unsigned u[8];
    #pragma unroll
    for (int j = 0; j < 8; ++j) u[j] = (unsigned)tmp[2*j] | ((unsigned)tmp[2*j+1] << 16);
    ushort* dst = vt + ((size_t)bh*HD + d)*SEQ + tt*64 + t0;
    *(uint4*)(dst)     = make_uint4(u[0],u[1],u[2],u[3]);
    *(uint4*)(dst + 8) = make_uint4(u[4],u[5],u[6],u[7]);
}

// ---------------- MFMA flash attention: direct-from-L2 K/V, barrier-free ----------------
// Both MFMA B-fragments are 8 CONSECUTIVE k-dim elements per lane, which
// matches row-major contiguity of k ([token][dim]) and vt ([d][key']): load
// them straight from global (L2-resident; XCD swizzle pins each bh-pair's
// 2 MB working set to one XCD L2). LDS holds ONLY the wave-private P
// round-trip -> zero __syncthreads in the whole kernel. 4 waves x 32 q,
// grid 512 (2 waves/SIMD fundamentals, the R6-optimal reuse/TLP point).
// q pre-scaled by 0.125*log2e -> P = exp2(S); row-sum l via ones-MFMA.
__global__ __launch_bounds__(256) void attn_mfma_kernel(
        const ushort* __restrict__ q, const ushort* __restrict__ k,
        const ushort* __restrict__ vt, ushort* __restrict__ out)
{
    __shared__ ushort Ps[4][32][72];   // per-wave P [qrow][key'] only

    int blk = blockIdx.x;
    int vx = blk & 7, idx = blk >> 3;          // XCD-locality swizzle
    int bh = vx*2 + (idx & 1);                 // 0..15, pinned per virtual XCD
    int qt = idx >> 1;                         // 0..31
    int b = bh >> 3, h = bh & 7;
    int tid = threadIdx.x;
    int w = tid >> 6, lane = tid & 63;
    int quad = lane >> 4, col = lane & 15;
    int qn0 = qt*128 + w*32;

    bf16x8 aq[2][2];    // [mtile][kchunk]
    #pragma unroll
    for (int mt = 0; mt < 2; ++mt) {
        const ushort* qp = q + (size_t)(b*SEQ + qn0 + mt*16 + col)*DIM + h*HD + quad*8;
        aq[mt][0] = *(const bf16x8*)(qp);
        aq[mt][1] = *(const bf16x8*)(qp + 32);
    }
    const short one_bf = (short)0x3F80;
    const bf16x8 ones = {one_bf,one_bf,one_bf,one_bf,one_bf,one_bf,one_bf,one_bf};

    f32x4 ot[2][4];
    f32x4 ol[2];
    #pragma unroll
    for (int mt = 0; mt < 2; ++mt) {
        ol[mt] = (f32x4){0.f,0.f,0.f,0.f};
        #pragma unroll
        for (int t4 = 0; t4 < 4; ++t4) ot[mt][t4] = (f32x4){0.f,0.f,0.f,0.f};
    }

    // per-lane base pointers for direct B-fragment loads
    // K frag (c,t4): k[(b*SEQ + t*64 + t4*16 + col)*DIM + h*HD + c*32 + quad*8]
    const ushort* kbase = k + (size_t)(b*SEQ + col)*DIM + h*HD + quad*8;
    // V frag (c,t4): vt[(bh*HD + t4*16 + col)*SEQ + t*64 + c*32 + quad*8]
    const ushort* vbase = vt + ((size_t)bh*HD + col)*SEQ + quad*8;

    for (int t = 0; t < SEQ/64; ++t) {
        // ---- direct global loads (L2 hits), no LDS staging, no barrier ----
        bf16x8 kf[2][4], vf[2][4];
        #pragma unroll
        for (int c = 0; c < 2; ++c)
            #pragma unroll
            for (int t4 = 0; t4 < 4; ++t4) {
                kf[c][t4] = *(const bf16x8*)(kbase + (size_t)(t*64 + t4*16)*DIM + c*32);
                vf[c][t4] = *(const bf16x8*)(vbase + (size_t)(t4*16)*SEQ + t*64 + c*32);
            }

        // S = Q K^T (log2-domain; q pre-scaled by 0.125*log2e)
        f32x4 sc[2][4];
        #pragma unroll
        for (int mt = 0; mt < 2; ++mt)
            #pragma unroll
            for (int t4 = 0; t4 < 4; ++t4) sc[mt][t4] = (f32x4){0.f,0.f,0.f,0.f};
        #pragma unroll
        for (int c = 0; c < 2; ++c)
            #pragma unroll
            for (int mt = 0; mt < 2; ++mt)
                #pragma unroll
                for (int t4 = 0; t4 < 4; ++t4)
                    sc[mt][t4] = __builtin_amdgcn_mfma_f32_16x16x32_bf16(aq[mt][c], kf[c][t4], sc[mt][t4], 0, 0, 0);

        // P = exp2(S); key' = col*4+t4 permutation packs 4 vals -> one 8B write
        #pragma unroll
        for (int mt = 0; mt < 2; ++mt)
            #pragma unroll
            for (int r = 0; r < 4; ++r) {
                uint2 pk;
                pk.x = pack2bf(EXP2(sc[mt][0][r]), EXP2(sc[mt][1][r]));
                pk.y = pack2bf(EXP2(sc[mt][2][r]), EXP2(sc[mt][3][r]));
                *(uint2*)&Ps[w][mt*16 + quad*4 + r][col*4] = pk;
            }

        // O += P V ; l += P @ 1  (vt rows already in permuted key' order)
        #pragma unroll
        for (int c = 0; c < 2; ++c)
            #pragma unroll
            for (int mt = 0; mt < 2; ++mt) {
                bf16x8 ap = *(const bf16x8*)&Ps[w][mt*16 + col][c*32 + quad*8];
                #pragma unroll
                for (int t4 = 0; t4 < 4; ++t4)
                    ot[mt][t4] = __builtin_amdgcn_mfma_f32_16x16x32_bf16(ap, vf[c][t4], ot[mt][t4], 0, 0, 0);
                ol[mt] = __builtin_amdgcn_mfma_f32_16x16x32_bf16(ap, ones, ol[mt], 0, 0, 0);
            }
    }

    #pragma unroll
    for (int mt = 0; mt < 2; ++mt)
        #pragma unroll
        for (int r = 0; r < 4; ++r) {
            float inv = 1.0f / ol[mt][r];
            #pragma unroll
            for (int t4 = 0; t4 < 4; ++t4)
                out[(size_t)(b*SEQ + qn0 + mt*16 + quad*4 + r)*DIM + h*HD + t4*16 + col]
                    = f2bf(ot[mt][t4][r] * inv);
        }
}

extern "C" void kernel_launch(void* const* d_in, const int* in_sizes, int n_in,
                              void* d_out, int out_size, void* d_ws, size_t ws_size,
                              hipStream_t stream)
{
    (void)in_sizes; (void)n_in; (void)out_size; (void)ws_size;
    const float* x   = (const float*)d_in[0];
    const float* Wq  = (const float*)d_in[1];
    const float* Wk  = (const float*)d_in[2];
    const float* Wv  = (const float*)d_in[3];
    const float* Wo  = (const float*)d_in[4];
    const float* bo  = (const float*)d_in[5];
    const float* W1  = (const float*)d_in[6];
    const float* b1  = (const float*)d_in[7];
    const float* W2  = (const float*)d_in[8];
    const float* b2  = (const float*)d_in[9];
    const float* g1  = (const float*)d_in[10];
    const float* be1 = (const float*)d_in[11];
    const float* g2  = (const float*)d_in[12];
    const float* be2 = (const float*)d_in[13];

    // workspace layout (ushort units)
    ushort* u = (ushort*)d_ws;
    float*  x2    = (float*)u;                       // [0, 2SZ) ushorts = SZ floats
    ushort* h     = u + 2*(size_t)SZ;                // [2SZ, 3SZ)
    ushort* qb    = u + 3*(size_t)SZ;                // [3SZ, 4SZ)
    ushort* kb    = u + 4*(size_t)SZ;
    ushort* vb    = u + 5*(size_t)SZ;
    ushort* vtb   = u + 6*(size_t)SZ;
    ushort* attnb = u + 7*(size_t)SZ;                // [7SZ, 8SZ)
    ushort* ff1   = u + 3*(size_t)SZ;                // overlays qb..vtb (dead by then), 4SZ
    ushort* wqkv  = u + 8*(size_t)SZ;                // 4x 512*512 (q,k,v,o)
    ushort* wto   = wqkv + 3*(size_t)512*512;
    ushort* wt1   = wqkv + 4*(size_t)512*512;        // [2048][512]
    ushort* wt2   = wt1  + (size_t)512*2048;         // [512][2048]
    float*  outp  = (float*)d_out;

    // weights -> bf16 transposed [N][K]
    wtrans4_kernel<<<dim3(8,8,4), 256, 0, stream>>>(Wq, Wk, Wv, Wo, wqkv);
    wtrans_kernel<<<dim3(32,8), 256, 0, stream>>>(W1, wt1, 512, 2048);
    wtrans_kernel<<<dim3(8,32), 256, 0, stream>>>(W2, wt2, 2048, 512);

    // h = LN(x) -> bf16
    ln_kernel<<<ROWS, 128, 0, stream>>>(x, g1, be1, h);
    // q,k,v = h @ {Wq,Wk,Wv} -> bf16 (q scaled by 0.125*log2e)
    gemm_bf16_kernel<128,256><<<dim3(1536/64, ROWS/128), 256, 0, stream>>>(
        h, wqkv, wqkv + (size_t)512*512, wqkv + 2*(size_t)512*512,
        nullptr, nullptr, qb, ROWS, 1536, DIM, 1);
    // vt = permuted transpose(v)
    vtrans_kernel<<<dim3(SEQ/64, BB*NH), 256, 0, stream>>>(vb, vtb);
    // attn = flash(q,k,v) -> bf16   (1D swizzled grid, 512 blocks)
    attn_mfma_kernel<<<dim3(512), 256, 0, stream>>>(qb, kb, vtb, attnb);
    // x2 = x + attn @ Wo + bo  (fp32)
    gemm_bf16_kernel<64,128><<<dim3(DIM/64, ROWS/64), 128, 0, stream>>>(
        attnb, wto, wto, wto, bo, x, x2, ROWS, DIM, DIM, 8|4);
    // h = LN(x2) -> bf16
    ln_kernel<<<ROWS, 128, 0, stream>>>(x2, g2, be2, h);
    // ff1 = gelu(h @ W1 + b1) -> bf16
    gemm_bf16_kernel<128,256><<<dim3(MLPD/64, ROWS/128), 256, 0, stream>>>(
        h, wt1, wt1, wt1, b1, nullptr, ff1, ROWS, MLPD, DIM, 8|2|16);
    // out = x2 + ff1 @ W2 + b2  (fp32)
    gemm_bf16_kernel<64,128><<<dim3(DIM/64, ROWS/64), 128, 0, stream>>>(
        ff1, wt2, wt2, wt2, b2, x2, outp, ROWS, DIM, MLPD, 8|4);
}

// Round 11
// 392.733 us; speedup vs baseline: 1.2911x; 1.2911x over previous
//
#include <hip/hip_runtime.h>
#include <math.h>

#define BB   2
#define SEQ  4096
#define DIM  512
#define NH   8
#define HD   64
#define MLPD 2048
#define ROWS (BB*SEQ)          /* 8192 */
#define SZ   (ROWS*DIM)        /* 4194304 elements */
#define EPSV 1e-5f

typedef __attribute__((ext_vector_type(8))) short bf16x8;   // A/B frag: 8 bf16
typedef __attribute__((ext_vector_type(4))) float f32x4;    // C/D frag: 4 f32

#if __has_builtin(__builtin_amdgcn_exp2f)
#define EXP2(x) __builtin_amdgcn_exp2f(x)
#else
#define EXP2(x) exp2f(x)
#endif

__device__ __forceinline__ ushort f2bf(float f) {           // RNE float->bf16
    unsigned u = __float_as_uint(f);
    u += 0x7fffu + ((u >> 16) & 1u);
    return (ushort)(u >> 16);
}
__device__ __forceinline__ unsigned pack2bf(float a, float b) {  // [b:a] packed
    return (unsigned)f2bf(a) | ((unsigned)f2bf(b) << 16);
}

__device__ __forceinline__ void gload16(const ushort* g, ushort* l) {
    __builtin_amdgcn_global_load_lds(
        (const __attribute__((address_space(1))) unsigned*)g,
        (__attribute__((address_space(3))) unsigned*)l, 16, 0, 0);
}

// ---------------- LayerNorm -> bf16 (one block = one row of 512) ----------------
__global__ __launch_bounds__(128) void ln_kernel(const float* __restrict__ x,
        const float* __restrict__ g, const float* __restrict__ be,
        ushort* __restrict__ out)
{
    int row = blockIdx.x;
    int tid = threadIdx.x;
    const float4 v = ((const float4*)(x + (size_t)row*DIM))[tid];
    float s  = v.x + v.y + v.z + v.w;
    float ss = v.x*v.x + v.y*v.y + v.z*v.z + v.w*v.w;
    #pragma unroll
    for (int off = 32; off > 0; off >>= 1) {
        s  += __shfl_down(s,  off);
        ss += __shfl_down(ss, off);
    }
    __shared__ float red[4];
    if ((tid & 63) == 0) { red[(tid>>6)*2+0] = s; red[(tid>>6)*2+1] = ss; }
    __syncthreads();
    float sum = red[0] + red[2], sumsq = red[1] + red[3];
    float mu  = sum * (1.0f/DIM);
    float var = sumsq * (1.0f/DIM) - mu*mu;
    float rs  = rsqrtf(var + EPSV);
    float4 gv = ((const float4*)g)[tid];
    float4 bv = ((const float4*)be)[tid];
    ushort4 o;
    o.x = f2bf((v.x - mu)*rs*gv.x + bv.x);
    o.y = f2bf((v.y - mu)*rs*gv.y + bv.y);
    o.z = f2bf((v.z - mu)*rs*gv.z + bv.z);
    o.w = f2bf((v.w - mu)*rs*gv.w + bv.w);
    ((ushort4*)(out + (size_t)row*DIM))[tid] = o;
}

// ---------------- Weight transpose-convert: fp32 [K][N] -> bf16 [N][K] ----------------
__global__ __launch_bounds__(256) void wtrans_kernel(const float* __restrict__ W,
        ushort* __restrict__ Wt, int K, int N)
{
    __shared__ ushort T[64][65];
    int n0 = blockIdx.x*64, k0 = blockIdx.y*64;
    int tid = threadIdx.x;
    #pragma unroll
    for (int p = 0; p < 4; ++p) {
        int r = p*16 + (tid>>4), c = (tid&15)<<2;
        float4 w4 = *(const float4*)(W + (size_t)(k0+r)*N + n0 + c);
        T[c+0][r] = f2bf(w4.x); T[c+1][r] = f2bf(w4.y);
        T[c+2][r] = f2bf(w4.z); T[c+3][r] = f2bf(w4.w);
    }
    __syncthreads();
    #pragma unroll
    for (int p = 0; p < 4; ++p) {
        int n = p*16 + (tid>>4), k = (tid&15)<<2;
        ushort4 o; o.x = T[n][k]; o.y = T[n][k+1]; o.z = T[n][k+2]; o.w = T[n][k+3];
        *(ushort4*)(Wt + (size_t)(n0+n)*K + k0 + k) = o;
    }
}

// 4x 512x512 weights in one launch (z selects)
__global__ __launch_bounds__(256) void wtrans4_kernel(
        const float* __restrict__ W0, const float* __restrict__ W1,
        const float* __restrict__ W2, const float* __restrict__ W3,
        ushort* __restrict__ Wt)
{
    __shared__ ushort T[64][65];
    int z = blockIdx.z;
    const float* W = (z==0) ? W0 : (z==1) ? W1 : (z==2) ? W2 : W3;
    ushort* Wtz = Wt + (size_t)z*512*512;
    int n0 = blockIdx.x*64, k0 = blockIdx.y*64;
    int tid = threadIdx.x;
    #pragma unroll
    for (int p = 0; p < 4; ++p) {
        int r = p*16 + (tid>>4), c = (tid&15)<<2;
        float4 w4 = *(const float4*)(W + (size_t)(k0+r)*512 + n0 + c);
        T[c+0][r] = f2bf(w4.x); T[c+1][r] = f2bf(w4.y);
        T[c+2][r] = f2bf(w4.z); T[c+3][r] = f2bf(w4.w);
    }
    __syncthreads();
    #pragma unroll
    for (int p = 0; p < 4; ++p) {
        int n = p*16 + (tid>>4), k = (tid&15)<<2;
        ushort4 o; o.x = T[n][k]; o.y = T[n][k+1]; o.z = T[n][k+2]; o.w = T[n][k+3];
        *(ushort4*)(Wtz + (size_t)(n0+n)*512 + k0 + k) = o;
    }
}

// ---------------- bf16 MFMA GEMM, BN=64, BK=32, double-buffered (R8-proven) ----------------
// flags: 1=QKV-split 2=GELU 4=+resid 8=+bias 16=bf16 out
template<int BM, int NT>
__global__ __launch_bounds__(NT) void gemm_bf16_kernel(
        const ushort* __restrict__ A,
        const ushort* __restrict__ Wta, const ushort* __restrict__ Wtb, const ushort* __restrict__ Wtc,
        const float* __restrict__ bias, const float* __restrict__ resid,
        void* __restrict__ outv, int M, int Nn, int K, int flags)
{
    constexpr int AISS = (BM*4)/NT;      // A-tile DMA issues
    constexpr int BISS = 256/NT;         // B-tile DMA issues
    __shared__ ushort As[2][BM*32];
    __shared__ ushort Bs[2][64*32];
    int tid = threadIdx.x;
    int w = tid >> 6, lane = tid & 63, quad = lane >> 4, col = lane & 15;
    int row0 = blockIdx.y * BM, col0 = blockIdx.x * 64;
    int wm0 = w * 32;

    const ushort* Wt; int wcol0, ostride, obase_col;
    float qscale = 1.0f;
    float* outF = nullptr; ushort* outB = nullptr;
    if (flags & 1) {
        int sel = col0 >> 9;
        Wt = (sel == 0) ? Wta : ((sel == 1) ? Wtb : Wtc);
        wcol0 = col0 & 511; ostride = 512; obase_col = wcol0;
        outB = (ushort*)outv + (size_t)sel * ((size_t)M * 512);
        if (sel == 0) qscale = 0.125f * 1.44269504088896f;  // 1/sqrt(HD) * log2(e)
        flags |= 16;
    } else {
        Wt = Wta; wcol0 = col0; ostride = Nn; obase_col = col0;
        if (flags & 16) outB = (ushort*)outv; else outF = (float*)outv;
    }

    f32x4 acc[2][4];
    #pragma unroll
    for (int i = 0; i < 2; ++i)
        #pragma unroll
        for (int j = 0; j < 4; ++j) acc[i][j] = (f32x4){0.f,0.f,0.f,0.f};

    const ushort* Ag = A  + (size_t)(row0  + (tid >> 2))*K + ((tid & 3) << 3);
    const ushort* Bg = Wt + (size_t)(wcol0 + (tid >> 2))*K + ((tid & 3) << 3);

    auto issue = [&](ushort* Ad, ushort* Bd, int ko) {
        #pragma unroll
        for (int it = 0; it < AISS; ++it)
            gload16(Ag + ko + (size_t)(it*(NT/4))*K, Ad + it*NT*8 + tid*8);
        #pragma unroll
        for (int it = 0; it < BISS; ++it)
            gload16(Bg + ko + (size_t)(it*(NT/4))*K, Bd + it*NT*8 + tid*8);
    };
    auto compute = [&](const ushort* Ab, const ushort* Bb) {
        bf16x8 af[2], bfr[4];
        #pragma unroll
        for (int i = 0; i < 2; ++i)
            af[i] = *(const bf16x8*)(Ab + (wm0 + i*16 + col)*32 + quad*8);
        #pragma unroll
        for (int j = 0; j < 4; ++j)
            bfr[j] = *(const bf16x8*)(Bb + (j*16 + col)*32 + quad*8);
        #pragma unroll
        for (int i = 0; i < 2; ++i)
            #pragma unroll
            for (int j = 0; j < 4; ++j)
                acc[i][j] = __builtin_amdgcn_mfma_f32_16x16x32_bf16(af[i], bfr[j], acc[i][j], 0, 0, 0);
    };

    int niter = K >> 5;                 // K/32, always even here
    issue(As[0], Bs[0], 0);
    for (int i = 0; i < niter; i += 2) {
        __syncthreads();                              // publish buf0 (DMA drained)
        if (i + 1 < niter) issue(As[1], Bs[1], (i+1)*32);   // prefetch overlaps compute
        compute(As[0], Bs[0]);
        __syncthreads();                              // publish buf1
        if (i + 2 < niter) issue(As[0], Bs[0], (i+2)*32);
        compute(As[1], Bs[1]);
    }

    #pragma unroll
    for (int i = 0; i < 2; ++i) {
        #pragma unroll
        for (int r = 0; r < 4; ++r) {
            int row = row0 + wm0 + i*16 + quad*4 + r;
            #pragma unroll
            for (int j = 0; j < 4; ++j) {
                int oc = obase_col + j*16 + col;
                float o = acc[i][j][r] * qscale;
                if (flags & 8) o += bias[oc];
                if (flags & 2) o = 0.5f*o*(1.f + erff(o*0.70710678118654752f));
                if (flags & 4) o += resid[(size_t)row*ostride + oc];
                if (flags & 16) outB[(size_t)row*ostride + oc] = f2bf(o);
                else            outF[(size_t)row*ostride + oc] = o;
            }
        }
    }
}

// ---------------- V transpose with PV-operand key permutation ----------------
// v[b,n,h*64+d] -> vt[bh][d][tile*64 + key'] where the original key for key'
// is korig = ((key'>>5)*2 + ((key'>>2)&1))*16 + ((key'>>3)&3)*4 + (key'&3).
// This matches the in-register repack of S^T C-layout -> P^T B-operand:
// (t4,quad,r) -> chunk c=t4>>1, j=(t4&1)*4+r, key' = c*32 + quad*8 + j.
__global__ __launch_bounds__(256) void vtrans_kernel(const ushort* __restrict__ v,
                                                     ushort* __restrict__ vt)
{
    int tt = blockIdx.x, bh = blockIdx.y;
    int b = bh >> 3, h = bh & 7;
    int tid = threadIdx.x;
    int d = tid >> 2, t0 = (tid & 3) << 4;     // 16 consecutive key' per thread
    ushort tmp[16];
    #pragma unroll
    for (int i = 0; i < 16; ++i) {
        int kp = t0 + i;
        int korig = ((kp>>5)*2 + ((kp>>2)&1))*16 + ((kp>>3)&3)*4 + (kp&3);
        tmp[i] = v[(size_t)(b*SEQ + tt*64 + korig)*DIM + h*HD + d];
    }
    unsigned u[8];
    #pragma unroll
    for (int j = 0; j < 8; ++j) u[j] = (unsigned)tmp[2*j] | ((unsigned)tmp[2*j+1] << 16);
    ushort* dst = vt + ((size_t)bh*HD + d)*SEQ + tt*64 + t0;
    *(uint4*)(dst)     = make_uint4(u[0],u[1],u[2],u[3]);
    *(uint4*)(dst + 8) = make_uint4(u[4],u[5],u[6],u[7]);
}

// ---------------- MFMA flash attention: S^T/O^T dataflow, P stays in registers ----------------
// S^T = K Q^T (A=K-frag, B=Q-frag): C-layout puts q on lanes (col) and keys on
// quad*4+r -- exactly the layout P^T needs as a B-operand after the in-register
// repack (t4,r)->(c,j). O^T = V^T P^T with V pre-permuted (vtrans): P NEVER
// goes through LDS. LDS = K/V staging only. 4 waves x 32 q (R6-optimal TLP),
// grid 512. q pre-scaled by 0.125*log2e -> P = exp2(S); l via ones-MFMA
// (all C rows equal -> 1 divide per 16q).
__global__ __launch_bounds__(256) void attn_mfma_kernel(
        const ushort* __restrict__ q, const ushort* __restrict__ k,
        const ushort* __restrict__ vt, ushort* __restrict__ out)
{
    __shared__ ushort Kt[64][72];      // [key][d]    stride 72: 2-way max (free)
    __shared__ ushort Vt[64][72];      // [d][key']   (key' = PV permutation)

    int qt = blockIdx.x, bh = blockIdx.y;
    int b = bh >> 3, h = bh & 7;
    int tid = threadIdx.x;
    int w = tid >> 6, lane = tid & 63;
    int quad = lane >> 4, col = lane & 15;
    int qn0 = qt*128 + w*32;

    bf16x8 aq[2][2];    // [mtile][kchunk]  (B-operand for S^T = Q^T)
    #pragma unroll
    for (int mt = 0; mt < 2; ++mt) {
        const ushort* qp = q + (size_t)(b*SEQ + qn0 + mt*16 + col)*DIM + h*HD + quad*8;
        aq[mt][0] = *(const bf16x8*)(qp);
        aq[mt][1] = *(const bf16x8*)(qp + 32);
    }
    const short one_bf = (short)0x3F80;
    const bf16x8 ones = {one_bf,one_bf,one_bf,one_bf,one_bf,one_bf,one_bf,one_bf};

    f32x4 ot[2][4];     // O^T tiles: [q-tile][d-tile]
    f32x4 ol[2];        // row sums
    #pragma unroll
    for (int mt = 0; mt < 2; ++mt) {
        ol[mt] = (f32x4){0.f,0.f,0.f,0.f};
        #pragma unroll
        for (int t4 = 0; t4 < 4; ++t4) ot[mt][t4] = (f32x4){0.f,0.f,0.f,0.f};
    }

    int skey = tid >> 2, sd0 = (tid & 3) << 4;   // staging: 32B per thread per matrix

    for (int t = 0; t < SEQ/64; ++t) {
        __syncthreads();
        {
            const ushort* kp = k + (size_t)(b*SEQ + t*64 + skey)*DIM + h*HD + sd0;
            *(bf16x8*)&Kt[skey][sd0]     = *(const bf16x8*)(kp);
            *(bf16x8*)&Kt[skey][sd0 + 8] = *(const bf16x8*)(kp + 8);
            const ushort* vp = vt + ((size_t)bh*HD + skey)*SEQ + t*64 + sd0;
            *(bf16x8*)&Vt[skey][sd0]     = *(const bf16x8*)(vp);
            *(bf16x8*)&Vt[skey][sd0 + 8] = *(const bf16x8*)(vp + 8);
        }
        __syncthreads();

        // S^T = K Q^T  (contraction over d; 2 chunks of 32)
        f32x4 sc[2][4];
        #pragma unroll
        for (int mt = 0; mt < 2; ++mt)
            #pragma unroll
            for (int t4 = 0; t4 < 4; ++t4) sc[mt][t4] = (f32x4){0.f,0.f,0.f,0.f};
        #pragma unroll
        for (int c = 0; c < 2; ++c) {
            bf16x8 kf[4];
            #pragma unroll
            for (int t4 = 0; t4 < 4; ++t4)
                kf[t4] = *(const bf16x8*)&Kt[t4*16 + col][c*32 + quad*8];
            #pragma unroll
            for (int mt = 0; mt < 2; ++mt)
                #pragma unroll
                for (int t4 = 0; t4 < 4; ++t4)
                    sc[mt][t4] = __builtin_amdgcn_mfma_f32_16x16x32_bf16(kf[t4], aq[mt][c], sc[mt][t4], 0, 0, 0);
        }

        // P^T = exp2(S^T), repacked in-register to B-operand layout:
        // chunk c elements j=0..3 <- sc[mt][2c][0..3], j=4..7 <- sc[mt][2c+1][0..3]
        union PU { bf16x8 v; uint4 u; };
        PU pb[2][2];
        #pragma unroll
        for (int mt = 0; mt < 2; ++mt)
            #pragma unroll
            for (int c = 0; c < 2; ++c) {
                pb[mt][c].u.x = pack2bf(EXP2(sc[mt][2*c  ][0]), EXP2(sc[mt][2*c  ][1]));
                pb[mt][c].u.y = pack2bf(EXP2(sc[mt][2*c  ][2]), EXP2(sc[mt][2*c  ][3]));
                pb[mt][c].u.z = pack2bf(EXP2(sc[mt][2*c+1][0]), EXP2(sc[mt][2*c+1][1]));
                pb[mt][c].u.w = pack2bf(EXP2(sc[mt][2*c+1][2]), EXP2(sc[mt][2*c+1][3]));
            }

        // O^T += V^T P^T ; l += 1 P^T   (keys permuted consistently in Vt)
        #pragma unroll
        for (int c = 0; c < 2; ++c) {
            bf16x8 vf[4];
            #pragma unroll
            for (int t4 = 0; t4 < 4; ++t4)
                vf[t4] = *(const bf16x8*)&Vt[t4*16 + col][c*32 + quad*8];
            #pragma unroll
            for (int mt = 0; mt < 2; ++mt) {
                #pragma unroll
                for (int t4 = 0; t4 < 4; ++t4)
                    ot[mt][t4] = __builtin_amdgcn_mfma_f32_16x16x32_bf16(vf[t4], pb[mt][c].v, ot[mt][t4], 0, 0, 0);
                ol[mt] = __builtin_amdgcn_mfma_f32_16x16x32_bf16(ones, pb[mt][c].v, ol[mt], 0, 0, 0);
            }
        }
    }

    // O^T C-layout: q = mt*16+col (lane), d = t4*16 + quad*4 + r -> contiguous
    // 4-element runs in d: one ushort4 store per (mt,t4).
    #pragma unroll
    for (int mt = 0; mt < 2; ++mt) {
        float inv = 1.0f / ol[mt][0];      // all C rows identical
        #pragma unroll
        for (int t4 = 0; t4 < 4; ++t4) {
            ushort4 o4;
            o4.x = f2bf(ot[mt][t4][0] * inv);
            o4.y = f2bf(ot[mt][t4][1] * inv);
            o4.z = f2bf(ot[mt][t4][2] * inv);
            o4.w = f2bf(ot[mt][t4][3] * inv);
            *(ushort4*)(out + (size_t)(b*SEQ + qn0 + mt*16 + col)*DIM + h*HD + t4*16 + quad*4) = o4;
        }
    }
}

extern "C" void kernel_launch(void* const* d_in, const int* in_sizes, int n_in,
                              void* d_out, int out_size, void* d_ws, size_t ws_size,
                              hipStream_t stream)
{
    (void)in_sizes; (void)n_in; (void)out_size; (void)ws_size;
    const float* x   = (const float*)d_in[0];
    const float* Wq  = (const float*)d_in[1];
    const float* Wk  = (const float*)d_in[2];
    const float* Wv  = (const float*)d_in[3];
    const float* Wo  = (const float*)d_in[4];
    const float* bo  = (const float*)d_in[5];
    const float* W1  = (const float*)d_in[6];
    const float* b1  = (const float*)d_in[7];
    const float* W2  = (const float*)d_in[8];
    const float* b2  = (const float*)d_in[9];
    const float* g1  = (const float*)d_in[10];
    const float* be1 = (const float*)d_in[11];
    const float* g2  = (const float*)d_in[12];
    const float* be2 = (const float*)d_in[13];

    // workspace layout (ushort units)
    ushort* u = (ushort*)d_ws;
    float*  x2    = (float*)u;                       // [0, 2SZ) ushorts = SZ floats
    ushort* h     = u + 2*(size_t)SZ;                // [2SZ, 3SZ)
    ushort* qb    = u + 3*(size_t)SZ;                // [3SZ, 4SZ)
    ushort* kb    = u + 4*(size_t)SZ;
    ushort* vb    = u + 5*(size_t)SZ;
    ushort* vtb   = u + 6*(size_t)SZ;
    ushort* attnb = u + 7*(size_t)SZ;                // [7SZ, 8SZ)
    ushort* ff1   = u + 3*(size_t)SZ;                // overlays qb..vtb (dead by then), 4SZ
    ushort* wqkv  = u + 8*(size_t)SZ;                // 4x 512*512 (q,k,v,o)
    ushort* wto   = wqkv + 3*(size_t)512*512;
    ushort* wt1   = wqkv + 4*(size_t)512*512;        // [2048][512]
    ushort* wt2   = wt1  + (size_t)512*2048;         // [512][2048]
    float*  outp  = (float*)d_out;

    // weights -> bf16 transposed [N][K]
    wtrans4_kernel<<<dim3(8,8,4), 256, 0, stream>>>(Wq, Wk, Wv, Wo, wqkv);
    wtrans_kernel<<<dim3(32,8), 256, 0, stream>>>(W1, wt1, 512, 2048);
    wtrans_kernel<<<dim3(8,32), 256, 0, stream>>>(W2, wt2, 2048, 512);

    // h = LN(x) -> bf16
    ln_kernel<<<ROWS, 128, 0, stream>>>(x, g1, be1, h);
    // q,k,v = h @ {Wq,Wk,Wv} -> bf16 (q scaled by 0.125*log2e)
    gemm_bf16_kernel<128,256><<<dim3(1536/64, ROWS/128), 256, 0, stream>>>(
        h, wqkv, wqkv + (size_t)512*512, wqkv + 2*(size_t)512*512,
        nullptr, nullptr, qb, ROWS, 1536, DIM, 1);
    // vt = permuted transpose(v)
    vtrans_kernel<<<dim3(SEQ/64, BB*NH), 256, 0, stream>>>(vb, vtb);
    // attn = flash(q,k,v) -> bf16
    attn_mfma_kernel<<<dim3(SEQ/128, BB*NH), 256, 0, stream>>>(qb, kb, vtb, attnb);
    // x2 = x + attn @ Wo + bo  (fp32)
    gemm_bf16_kernel<64,128><<<dim3(DIM/64, ROWS/64), 128, 0, stream>>>(
        attnb, wto, wto, wto, bo, x, x2, ROWS, DIM, DIM, 8|4);
    // h = LN(x2) -> bf16
    ln_kernel<<<ROWS, 128, 0, stream>>>(x2, g2, be2, h);
    // ff1 = gelu(h @ W1 + b1) -> bf16
    gemm_bf16_kernel<128,256><<<dim3(MLPD/64, ROWS/128), 256, 0, stream>>>(
        h, wt1, wt1, wt1, b1, nullptr, ff1, ROWS, MLPD, DIM, 8|2|16);
    // out = x2 + ff1 @ W2 + b2  (fp32)
    gemm_bf16_kernel<64,128><<<dim3(DIM/64, ROWS/64), 128, 0, stream>>>(
        ff1, wt2, wt2, wt2, b2, x2, outp, ROWS, DIM, MLPD, 8|4);
}

// Round 12
// 388.776 us; speedup vs baseline: 1.3042x; 1.0102x over previous
//
#include <hip/hip_runtime.h>
#include <math.h>

#define BB   2
#define SEQ  4096
#define DIM  512
#define NH   8
#define HD   64
#define MLPD 2048
#define ROWS (BB*SEQ)          /* 8192 */
#define SZ   (ROWS*DIM)        /* 4194304 elements */
#define EPSV 1e-5f

typedef __attribute__((ext_vector_type(8))) short bf16x8;   // A/B frag: 8 bf16
typedef __attribute__((ext_vector_type(4))) float f32x4;    // C/D frag: 4 f32

#if __has_builtin(__builtin_amdgcn_exp2f)
#define EXP2(x) __builtin_amdgcn_exp2f(x)
#else
#define EXP2(x) exp2f(x)
#endif

__device__ __forceinline__ ushort f2bf(float f) {           // RNE float->bf16
    unsigned u = __float_as_uint(f);
    u += 0x7fffu + ((u >> 16) & 1u);
    return (ushort)(u >> 16);
}
__device__ __forceinline__ unsigned pack2bf(float a, float b) {  // [b:a] packed
    return (unsigned)f2bf(a) | ((unsigned)f2bf(b) << 16);
}

__device__ __forceinline__ void gload16(const ushort* g, ushort* l) {
    __builtin_amdgcn_global_load_lds(
        (const __attribute__((address_space(1))) unsigned*)g,
        (__attribute__((address_space(3))) unsigned*)l, 16, 0, 0);
}

// ---------------- LayerNorm -> bf16 (one block = one row of 512) ----------------
__global__ __launch_bounds__(128) void ln_kernel(const float* __restrict__ x,
        const float* __restrict__ g, const float* __restrict__ be,
        ushort* __restrict__ out)
{
    int row = blockIdx.x;
    int tid = threadIdx.x;
    const float4 v = ((const float4*)(x + (size_t)row*DIM))[tid];
    float s  = v.x + v.y + v.z + v.w;
    float ss = v.x*v.x + v.y*v.y + v.z*v.z + v.w*v.w;
    #pragma unroll
    for (int off = 32; off > 0; off >>= 1) {
        s  += __shfl_down(s,  off);
        ss += __shfl_down(ss, off);
    }
    __shared__ float red[4];
    if ((tid & 63) == 0) { red[(tid>>6)*2+0] = s; red[(tid>>6)*2+1] = ss; }
    __syncthreads();
    float sum = red[0] + red[2], sumsq = red[1] + red[3];
    float mu  = sum * (1.0f/DIM);
    float var = sumsq * (1.0f/DIM) - mu*mu;
    float rs  = rsqrtf(var + EPSV);
    float4 gv = ((const float4*)g)[tid];
    float4 bv = ((const float4*)be)[tid];
    ushort4 o;
    o.x = f2bf((v.x - mu)*rs*gv.x + bv.x);
    o.y = f2bf((v.y - mu)*rs*gv.y + bv.y);
    o.z = f2bf((v.z - mu)*rs*gv.z + bv.z);
    o.w = f2bf((v.w - mu)*rs*gv.w + bv.w);
    ((ushort4*)(out + (size_t)row*DIM))[tid] = o;
}

// ---------------- Weight transpose-convert: fp32 [K][N] -> bf16 [N][K] ----------------
__global__ __launch_bounds__(256) void wtrans_kernel(const float* __restrict__ W,
        ushort* __restrict__ Wt, int K, int N)
{
    __shared__ ushort T[64][65];
    int n0 = blockIdx.x*64, k0 = blockIdx.y*64;
    int tid = threadIdx.x;
    #pragma unroll
    for (int p = 0; p < 4; ++p) {
        int r = p*16 + (tid>>4), c = (tid&15)<<2;
        float4 w4 = *(const float4*)(W + (size_t)(k0+r)*N + n0 + c);
        T[c+0][r] = f2bf(w4.x); T[c+1][r] = f2bf(w4.y);
        T[c+2][r] = f2bf(w4.z); T[c+3][r] = f2bf(w4.w);
    }
    __syncthreads();
    #pragma unroll
    for (int p = 0; p < 4; ++p) {
        int n = p*16 + (tid>>4), k = (tid&15)<<2;
        ushort4 o; o.x = T[n][k]; o.y = T[n][k+1]; o.z = T[n][k+2]; o.w = T[n][k+3];
        *(ushort4*)(Wt + (size_t)(n0+n)*K + k0 + k) = o;
    }
}

// 4x 512x512 weights in one launch (z selects)
__global__ __launch_bounds__(256) void wtrans4_kernel(
        const float* __restrict__ W0, const float* __restrict__ W1,
        const float* __restrict__ W2, const float* __restrict__ W3,
        ushort* __restrict__ Wt)
{
    __shared__ ushort T[64][65];
    int z = blockIdx.z;
    const float* W = (z==0) ? W0 : (z==1) ? W1 : (z==2) ? W2 : W3;
    ushort* Wtz = Wt + (size_t)z*512*512;
    int n0 = blockIdx.x*64, k0 = blockIdx.y*64;
    int tid = threadIdx.x;
    #pragma unroll
    for (int p = 0; p < 4; ++p) {
        int r = p*16 + (tid>>4), c = (tid&15)<<2;
        float4 w4 = *(const float4*)(W + (size_t)(k0+r)*512 + n0 + c);
        T[c+0][r] = f2bf(w4.x); T[c+1][r] = f2bf(w4.y);
        T[c+2][r] = f2bf(w4.z); T[c+3][r] = f2bf(w4.w);
    }
    __syncthreads();
    #pragma unroll
    for (int p = 0; p < 4; ++p) {
        int n = p*16 + (tid>>4), k = (tid&15)<<2;
        ushort4 o; o.x = T[n][k]; o.y = T[n][k+1]; o.z = T[n][k+2]; o.w = T[n][k+3];
        *(ushort4*)(Wtz + (size_t)(n0+n)*512 + k0 + k) = o;
    }
}

// ---------------- bf16 MFMA GEMM, BN=64, BK=32, double-buffered (R8-proven) ----------------
// Used for Wo/W2 (N=512): grid stays large. flags: 2=GELU 4=+resid 8=+bias 16=bf16 out
template<int BM, int NT>
__global__ __launch_bounds__(NT) void gemm_bf16_kernel(
        const ushort* __restrict__ A, const ushort* __restrict__ Wt,
        const float* __restrict__ bias, const float* __restrict__ resid,
        void* __restrict__ outv, int M, int Nn, int K, int flags)
{
    constexpr int AISS = (BM*4)/NT;
    constexpr int BISS = 256/NT;
    __shared__ ushort As[2][BM*32];
    __shared__ ushort Bs[2][64*32];
    int tid = threadIdx.x;
    int w = tid >> 6, lane = tid & 63, quad = lane >> 4, col = lane & 15;
    int row0 = blockIdx.y * BM, col0 = blockIdx.x * 64;
    int wm0 = w * 32;

    float* outF = nullptr; ushort* outB = nullptr;
    if (flags & 16) outB = (ushort*)outv; else outF = (float*)outv;

    f32x4 acc[2][4];
    #pragma unroll
    for (int i = 0; i < 2; ++i)
        #pragma unroll
        for (int j = 0; j < 4; ++j) acc[i][j] = (f32x4){0.f,0.f,0.f,0.f};

    const ushort* Ag = A  + (size_t)(row0 + (tid >> 2))*K + ((tid & 3) << 3);
    const ushort* Bg = Wt + (size_t)(col0 + (tid >> 2))*K + ((tid & 3) << 3);

    auto issue = [&](ushort* Ad, ushort* Bd, int ko) {
        #pragma unroll
        for (int it = 0; it < AISS; ++it)
            gload16(Ag + ko + (size_t)(it*(NT/4))*K, Ad + it*NT*8 + tid*8);
        #pragma unroll
        for (int it = 0; it < BISS; ++it)
            gload16(Bg + ko + (size_t)(it*(NT/4))*K, Bd + it*NT*8 + tid*8);
    };
    auto compute = [&](const ushort* Ab, const ushort* Bb) {
        bf16x8 af[2], bfr[4];
        #pragma unroll
        for (int i = 0; i < 2; ++i)
            af[i] = *(const bf16x8*)(Ab + (wm0 + i*16 + col)*32 + quad*8);
        #pragma unroll
        for (int j = 0; j < 4; ++j)
            bfr[j] = *(const bf16x8*)(Bb + (j*16 + col)*32 + quad*8);
        #pragma unroll
        for (int i = 0; i < 2; ++i)
            #pragma unroll
            for (int j = 0; j < 4; ++j)
                acc[i][j] = __builtin_amdgcn_mfma_f32_16x16x32_bf16(af[i], bfr[j], acc[i][j], 0, 0, 0);
    };

    int niter = K >> 5;
    issue(As[0], Bs[0], 0);
    for (int i = 0; i < niter; i += 2) {
        __syncthreads();
        if (i + 1 < niter) issue(As[1], Bs[1], (i+1)*32);
        compute(As[0], Bs[0]);
        __syncthreads();
        if (i + 2 < niter) issue(As[0], Bs[0], (i+2)*32);
        compute(As[1], Bs[1]);
    }

    #pragma unroll
    for (int i = 0; i < 2; ++i) {
        #pragma unroll
        for (int r = 0; r < 4; ++r) {
            int row = row0 + wm0 + i*16 + quad*4 + r;
            #pragma unroll
            for (int j = 0; j < 4; ++j) {
                int oc = col0 + j*16 + col;
                float o = acc[i][j][r];
                if (flags & 8) o += bias[oc];
                if (flags & 2) o = 0.5f*o*(1.f + erff(o*0.70710678118654752f));
                if (flags & 4) o += resid[(size_t)row*Nn + oc];
                if (flags & 16) outB[(size_t)row*Nn + oc] = f2bf(o);
                else            outF[(size_t)row*Nn + oc] = o;
            }
        }
    }
}

// ---------------- bf16 MFMA GEMM 128x128, wave-tile 64x64, dbuf BK=32 ----------------
// For QKV (flags&1) and W1: 2.0 MFMA per b128 LDS read (vs 1.33 in the 64-wide
// template) -- attacks the LDS-read-bound regime. 4 waves in 2x2.
__global__ __launch_bounds__(256) void gemm128_kernel(
        const ushort* __restrict__ A,
        const ushort* __restrict__ Wta, const ushort* __restrict__ Wtb, const ushort* __restrict__ Wtc,
        const float* __restrict__ bias, const float* __restrict__ resid,
        void* __restrict__ outv, int M, int Nn, int K, int flags)
{
    __shared__ ushort As[2][128*32];    // 16 KB
    __shared__ ushort Bs[2][128*32];    // 16 KB
    int tid = threadIdx.x;
    int w = tid >> 6, lane = tid & 63, quad = lane >> 4, col = lane & 15;
    int row0 = blockIdx.y * 128, col0 = blockIdx.x * 128;
    int wm0 = (w >> 1) * 64, wn0 = (w & 1) * 64;

    const ushort* Wt; int wcol0, ostride, obase_col;
    float qscale = 1.0f;
    float* outF = nullptr; ushort* outB = nullptr;
    if (flags & 1) {
        int sel = col0 >> 9;
        Wt = (sel == 0) ? Wta : ((sel == 1) ? Wtb : Wtc);
        wcol0 = col0 & 511; ostride = 512; obase_col = wcol0;
        outB = (ushort*)outv + (size_t)sel * ((size_t)M * 512);
        if (sel == 0) qscale = 0.125f * 1.44269504088896f;  // 1/sqrt(HD) * log2(e)
        flags |= 16;
    } else {
        Wt = Wta; wcol0 = col0; ostride = Nn; obase_col = col0;
        if (flags & 16) outB = (ushort*)outv; else outF = (float*)outv;
    }

    f32x4 acc[4][4];
    #pragma unroll
    for (int i = 0; i < 4; ++i)
        #pragma unroll
        for (int j = 0; j < 4; ++j) acc[i][j] = (f32x4){0.f,0.f,0.f,0.f};

    const ushort* Ag = A  + (size_t)(row0  + (tid >> 2))*K + ((tid & 3) << 3);
    const ushort* Bg = Wt + (size_t)(wcol0 + (tid >> 2))*K + ((tid & 3) << 3);
    size_t i64K = (size_t)64*K;

    auto issue = [&](ushort* Ad, ushort* Bd, int ko) {
        gload16(Ag + ko,        Ad + tid*8);
        gload16(Ag + ko + i64K, Ad + 2048 + tid*8);
        gload16(Bg + ko,        Bd + tid*8);
        gload16(Bg + ko + i64K, Bd + 2048 + tid*8);
    };
    auto compute = [&](const ushort* Ab, const ushort* Bb) {
        bf16x8 af[4], bfr[4];
        #pragma unroll
        for (int i = 0; i < 4; ++i) {
            af[i]  = *(const bf16x8*)(Ab + (wm0 + i*16 + col)*32 + quad*8);
            bfr[i] = *(const bf16x8*)(Bb + (wn0 + i*16 + col)*32 + quad*8);
        }
        #pragma unroll
        for (int i = 0; i < 4; ++i)
            #pragma unroll
            for (int j = 0; j < 4; ++j)
                acc[i][j] = __builtin_amdgcn_mfma_f32_16x16x32_bf16(af[i], bfr[j], acc[i][j], 0, 0, 0);
    };

    int niter = K >> 5;                 // even for K=512
    issue(As[0], Bs[0], 0);
    for (int i = 0; i < niter; i += 2) {
        __syncthreads();
        if (i + 1 < niter) issue(As[1], Bs[1], (i+1)*32);
        compute(As[0], Bs[0]);
        __syncthreads();
        if (i + 2 < niter) issue(As[0], Bs[0], (i+2)*32);
        compute(As[1], Bs[1]);
    }

    #pragma unroll
    for (int i = 0; i < 4; ++i) {
        #pragma unroll
        for (int r = 0; r < 4; ++r) {
            int row = row0 + wm0 + i*16 + quad*4 + r;
            #pragma unroll
            for (int j = 0; j < 4; ++j) {
                int oc = obase_col + wn0 + j*16 + col;
                float o = acc[i][j][r] * qscale;
                if (flags & 8) o += bias[oc];
                if (flags & 2) o = 0.5f*o*(1.f + erff(o*0.70710678118654752f));
                if (flags & 4) o += resid[(size_t)row*ostride + oc];
                if (flags & 16) outB[(size_t)row*ostride + oc] = f2bf(o);
                else            outF[(size_t)row*ostride + oc] = o;
            }
        }
    }
}

// ---------------- V transpose with PV-operand key permutation ----------------
// korig = ((key'>>5)*2 + ((key'>>2)&1))*16 + ((key'>>3)&3)*4 + (key'&3).
__global__ __launch_bounds__(256) void vtrans_kernel(const ushort* __restrict__ v,
                                                     ushort* __restrict__ vt)
{
    int tt = blockIdx.x, bh = blockIdx.y;
    int b = bh >> 3, h = bh & 7;
    int tid = threadIdx.x;
    int d = tid >> 2, t0 = (tid & 3) << 4;
    ushort tmp[16];
    #pragma unroll
    for (int i = 0; i < 16; ++i) {
        int kp = t0 + i;
        int korig = ((kp>>5)*2 + ((kp>>2)&1))*16 + ((kp>>3)&3)*4 + (kp&3);
        tmp[i] = v[(size_t)(b*SEQ + tt*64 + korig)*DIM + h*HD + d];
    }
    unsigned u[8];
    #pragma unroll
    for (int j = 0; j < 8; ++j) u[j] = (unsigned)tmp[2*j] | ((unsigned)tmp[2*j+1] << 16);
    ushort* dst = vt + ((size_t)bh*HD + d)*SEQ + tt*64 + t0;
    *(uint4*)(dst)     = make_uint4(u[0],u[1],u[2],u[3]);
    *(uint4*)(dst + 8) = make_uint4(u[4],u[5],u[6],u[7]);
}

// ---------------- MFMA flash attention: S^T/O^T, P-in-registers, dbuf K/V ----------------
// R11 dataflow (P never touches LDS) + double-buffered staging: prefetch
// tile t+1 into registers during compute of t, store to buf p^1, ONE barrier
// per iteration. Global load latency fully hidden behind 36 MFMAs + softmax.
__global__ __launch_bounds__(256) void attn_mfma_kernel(
        const ushort* __restrict__ q, const ushort* __restrict__ k,
        const ushort* __restrict__ vt, ushort* __restrict__ out)
{
    __shared__ ushort Kt[2][64][72];
    __shared__ ushort Vt[2][64][72];

    int qt = blockIdx.x, bh = blockIdx.y;
    int b = bh >> 3, h = bh & 7;
    int tid = threadIdx.x;
    int w = tid >> 6, lane = tid & 63;
    int quad = lane >> 4, col = lane & 15;
    int qn0 = qt*128 + w*32;

    bf16x8 aq[2][2];    // Q^T B-operand, resident
    #pragma unroll
    for (int mt = 0; mt < 2; ++mt) {
        const ushort* qp = q + (size_t)(b*SEQ + qn0 + mt*16 + col)*DIM + h*HD + quad*8;
        aq[mt][0] = *(const bf16x8*)(qp);
        aq[mt][1] = *(const bf16x8*)(qp + 32);
    }
    const short one_bf = (short)0x3F80;
    const bf16x8 ones = {one_bf,one_bf,one_bf,one_bf,one_bf,one_bf,one_bf,one_bf};

    f32x4 ot[2][4];
    f32x4 ol[2];
    #pragma unroll
    for (int mt = 0; mt < 2; ++mt) {
        ol[mt] = (f32x4){0.f,0.f,0.f,0.f};
        #pragma unroll
        for (int t4 = 0; t4 < 4; ++t4) ot[mt][t4] = (f32x4){0.f,0.f,0.f,0.f};
    }

    int skey = tid >> 2, sd0 = (tid & 3) << 4;
    bf16x8 kr[2], vr[2];
    auto load_tile = [&](int t) {
        const ushort* kp = k + (size_t)(b*SEQ + t*64 + skey)*DIM + h*HD + sd0;
        kr[0] = *(const bf16x8*)(kp);
        kr[1] = *(const bf16x8*)(kp + 8);
        const ushort* vp = vt + ((size_t)bh*HD + skey)*SEQ + t*64 + sd0;
        vr[0] = *(const bf16x8*)(vp);
        vr[1] = *(const bf16x8*)(vp + 8);
    };
    auto store_tile = [&](int p) {
        *(bf16x8*)&Kt[p][skey][sd0]     = kr[0];
        *(bf16x8*)&Kt[p][skey][sd0+8]   = kr[1];
        *(bf16x8*)&Vt[p][skey][sd0]     = vr[0];
        *(bf16x8*)&Vt[p][skey][sd0+8]   = vr[1];
    };

    load_tile(0);
    store_tile(0);
    __syncthreads();

    for (int t = 0; t < SEQ/64; ++t) {
        int p = t & 1;
        if (t + 1 < SEQ/64) load_tile(t + 1);     // VMEM in flight over compute

        // S^T = K Q^T
        f32x4 sc[2][4];
        #pragma unroll
        for (int mt = 0; mt < 2; ++mt)
            #pragma unroll
            for (int t4 = 0; t4 < 4; ++t4) sc[mt][t4] = (f32x4){0.f,0.f,0.f,0.f};
        #pragma unroll
        for (int c = 0; c < 2; ++c) {
            bf16x8 kf[4];
            #pragma unroll
            for (int t4 = 0; t4 < 4; ++t4)
                kf[t4] = *(const bf16x8*)&Kt[p][t4*16 + col][c*32 + quad*8];
            #pragma unroll
            for (int mt = 0; mt < 2; ++mt)
                #pragma unroll
                for (int t4 = 0; t4 < 4; ++t4)
                    sc[mt][t4] = __builtin_amdgcn_mfma_f32_16x16x32_bf16(kf[t4], aq[mt][c], sc[mt][t4], 0, 0, 0);
        }

        // P^T = exp2(S^T), in-register repack to B-operand layout
        union PU { bf16x8 v; uint4 u; };
        PU pb[2][2];
        #pragma unroll
        for (int mt = 0; mt < 2; ++mt)
            #pragma unroll
            for (int c = 0; c < 2; ++c) {
                pb[mt][c].u.x = pack2bf(EXP2(sc[mt][2*c  ][0]), EXP2(sc[mt][2*c  ][1]));
                pb[mt][c].u.y = pack2bf(EXP2(sc[mt][2*c  ][2]), EXP2(sc[mt][2*c  ][3]));
                pb[mt][c].u.z = pack2bf(EXP2(sc[mt][2*c+1][0]), EXP2(sc[mt][2*c+1][1]));
                pb[mt][c].u.w = pack2bf(EXP2(sc[mt][2*c+1][2]), EXP2(sc[mt][2*c+1][3]));
            }

        // O^T += V^T P^T ; l += 1 P^T
        #pragma unroll
        for (int c = 0; c < 2; ++c) {
            bf16x8 vf[4];
            #pragma unroll
            for (int t4 = 0; t4 < 4; ++t4)
                vf[t4] = *(const bf16x8*)&Vt[p][t4*16 + col][c*32 + quad*8];
            #pragma unroll
            for (int mt = 0; mt < 2; ++mt) {
                #pragma unroll
                for (int t4 = 0; t4 < 4; ++t4)
                    ot[mt][t4] = __builtin_amdgcn_mfma_f32_16x16x32_bf16(vf[t4], pb[mt][c].v, ot[mt][t4], 0, 0, 0);
                ol[mt] = __builtin_amdgcn_mfma_f32_16x16x32_bf16(ones, pb[mt][c].v, ol[mt], 0, 0, 0);
            }
        }

        if (t + 1 < SEQ/64) store_tile(p ^ 1);    // tile t-1 fully consumed pre-barrier
        __syncthreads();
    }

    #pragma unroll
    for (int mt = 0; mt < 2; ++mt) {
        float inv = 1.0f / ol[mt][0];
        #pragma unroll
        for (int t4 = 0; t4 < 4; ++t4) {
            ushort4 o4;
            o4.x = f2bf(ot[mt][t4][0] * inv);
            o4.y = f2bf(ot[mt][t4][1] * inv);
            o4.z = f2bf(ot[mt][t4][2] * inv);
            o4.w = f2bf(ot[mt][t4][3] * inv);
            *(ushort4*)(out + (size_t)(b*SEQ + qn0 + mt*16 + col)*DIM + h*HD + t4*16 + quad*4) = o4;
        }
    }
}

extern "C" void kernel_launch(void* const* d_in, const int* in_sizes, int n_in,
                              void* d_out, int out_size, void* d_ws, size_t ws_size,
                              hipStream_t stream)
{
    (void)in_sizes; (void)n_in; (void)out_size; (void)ws_size;
    const float* x   = (const float*)d_in[0];
    const float* Wq  = (const float*)d_in[1];
    const float* Wk  = (const float*)d_in[2];
    const float* Wv  = (const float*)d_in[3];
    const float* Wo  = (const float*)d_in[4];
    const float* bo  = (const float*)d_in[5];
    const float* W1  = (const float*)d_in[6];
    const float* b1  = (const float*)d_in[7];
    const float* W2  = (const float*)d_in[8];
    const float* b2  = (const float*)d_in[9];
    const float* g1  = (const float*)d_in[10];
    const float* be1 = (const float*)d_in[11];
    const float* g2  = (const float*)d_in[12];
    const float* be2 = (const float*)d_in[13];

    // workspace layout (ushort units)
    ushort* u = (ushort*)d_ws;
    float*  x2    = (float*)u;                       // [0, 2SZ) ushorts = SZ floats
    ushort* h     = u + 2*(size_t)SZ;                // [2SZ, 3SZ)
    ushort* qb    = u + 3*(size_t)SZ;                // [3SZ, 4SZ)
    ushort* kb    = u + 4*(size_t)SZ;
    ushort* vb    = u + 5*(size_t)SZ;
    ushort* vtb   = u + 6*(size_t)SZ;
    ushort* attnb = u + 7*(size_t)SZ;                // [7SZ, 8SZ)
    ushort* ff1   = u + 3*(size_t)SZ;                // overlays qb..vtb (dead by then), 4SZ
    ushort* wqkv  = u + 8*(size_t)SZ;                // 4x 512*512 (q,k,v,o)
    ushort* wto   = wqkv + 3*(size_t)512*512;
    ushort* wt1   = wqkv + 4*(size_t)512*512;        // [2048][512]
    ushort* wt2   = wt1  + (size_t)512*2048;         // [512][2048]
    float*  outp  = (float*)d_out;

    // weights -> bf16 transposed [N][K]
    wtrans4_kernel<<<dim3(8,8,4), 256, 0, stream>>>(Wq, Wk, Wv, Wo, wqkv);
    wtrans_kernel<<<dim3(32,8), 256, 0, stream>>>(W1, wt1, 512, 2048);
    wtrans_kernel<<<dim3(8,32), 256, 0, stream>>>(W2, wt2, 2048, 512);

    // h = LN(x) -> bf16
    ln_kernel<<<ROWS, 128, 0, stream>>>(x, g1, be1, h);
    // q,k,v = h @ {Wq,Wk,Wv} -> bf16 (q scaled by 0.125*log2e)  [128x128 kernel]
    gemm128_kernel<<<dim3(1536/128, ROWS/128), 256, 0, stream>>>(
        h, wqkv, wqkv + (size_t)512*512, wqkv + 2*(size_t)512*512,
        nullptr, nullptr, qb, ROWS, 1536, DIM, 1);
    // vt = permuted transpose(v)
    vtrans_kernel<<<dim3(SEQ/64, BB*NH), 256, 0, stream>>>(vb, vtb);
    // attn = flash(q,k,v) -> bf16
    attn_mfma_kernel<<<dim3(SEQ/128, BB*NH), 256, 0, stream>>>(qb, kb, vtb, attnb);
    // x2 = x + attn @ Wo + bo  (fp32)
    gemm_bf16_kernel<64,128><<<dim3(DIM/64, ROWS/64), 128, 0, stream>>>(
        attnb, wto, bo, x, x2, ROWS, DIM, DIM, 8|4);
    // h = LN(x2) -> bf16
    ln_kernel<<<ROWS, 128, 0, stream>>>(x2, g2, be2, h);
    // ff1 = gelu(h @ W1 + b1) -> bf16  [128x128 kernel]
    gemm128_kernel<<<dim3(MLPD/128, ROWS/128), 256, 0, stream>>>(
        h, wt1, wt1, wt1, b1, nullptr, ff1, ROWS, MLPD, DIM, 8|2|16);
    // out = x2 + ff1 @ W2 + b2  (fp32)
    gemm_bf16_kernel<64,128><<<dim3(DIM/64, ROWS/64), 128, 0, stream>>>(
        ff1, wt2, b2, x2, outp, ROWS, DIM, MLPD, 8|4);
}

// Round 13
// 364.279 us; speedup vs baseline: 1.3919x; 1.0672x over previous
//
#include <hip/hip_runtime.h>
#include <math.h>

#define BB   2
#define SEQ  4096
#define DIM  512
#define NH   8
#define HD   64
#define MLPD 2048
#define ROWS (BB*SEQ)          /* 8192 */
#define SZ   (ROWS*DIM)        /* 4194304 elements */
#define EPSV 1e-5f

typedef __attribute__((ext_vector_type(8))) short bf16x8;   // A/B frag: 8 bf16
typedef __attribute__((ext_vector_type(4))) float f32x4;    // C/D frag: 4 f32

#if __has_builtin(__builtin_amdgcn_exp2f)
#define EXP2(x) __builtin_amdgcn_exp2f(x)
#else
#define EXP2(x) exp2f(x)
#endif

__device__ __forceinline__ ushort f2bf(float f) {           // RNE float->bf16
    unsigned u = __float_as_uint(f);
    u += 0x7fffu + ((u >> 16) & 1u);
    return (ushort)(u >> 16);
}
__device__ __forceinline__ unsigned pack2bf(float a, float b) {  // RNE [b:a]
    return (unsigned)f2bf(a) | ((unsigned)f2bf(b) << 16);
}
__device__ __forceinline__ unsigned pack2bf_tr(float a, float b) { // trunc [b:a], 1 op
    return (__float_as_uint(a) >> 16) | (__float_as_uint(b) & 0xffff0000u);
}

__device__ __forceinline__ void gload16(const ushort* g, ushort* l) {
    __builtin_amdgcn_global_load_lds(
        (const __attribute__((address_space(1))) unsigned*)g,
        (__attribute__((address_space(3))) unsigned*)l, 16, 0, 0);
}

// ---------------- LayerNorm -> bf16 (one block = one row of 512) ----------------
__global__ __launch_bounds__(128) void ln_kernel(const float* __restrict__ x,
        const float* __restrict__ g, const float* __restrict__ be,
        ushort* __restrict__ out)
{
    int row = blockIdx.x;
    int tid = threadIdx.x;
    const float4 v = ((const float4*)(x + (size_t)row*DIM))[tid];
    float s  = v.x + v.y + v.z + v.w;
    float ss = v.x*v.x + v.y*v.y + v.z*v.z + v.w*v.w;
    #pragma unroll
    for (int off = 32; off > 0; off >>= 1) {
        s  += __shfl_down(s,  off);
        ss += __shfl_down(ss, off);
    }
    __shared__ float red[4];
    if ((tid & 63) == 0) { red[(tid>>6)*2+0] = s; red[(tid>>6)*2+1] = ss; }
    __syncthreads();
    float sum = red[0] + red[2], sumsq = red[1] + red[3];
    float mu  = sum * (1.0f/DIM);
    float var = sumsq * (1.0f/DIM) - mu*mu;
    float rs  = rsqrtf(var + EPSV);
    float4 gv = ((const float4*)g)[tid];
    float4 bv = ((const float4*)be)[tid];
    ushort4 o;
    o.x = f2bf((v.x - mu)*rs*gv.x + bv.x);
    o.y = f2bf((v.y - mu)*rs*gv.y + bv.y);
    o.z = f2bf((v.z - mu)*rs*gv.z + bv.z);
    o.w = f2bf((v.w - mu)*rs*gv.w + bv.w);
    ((ushort4*)(out + (size_t)row*DIM))[tid] = o;
}

// ---------------- Weight transpose-convert: fp32 [K][N] -> bf16 [N][K] ----------------
__global__ __launch_bounds__(256) void wtrans_kernel(const float* __restrict__ W,
        ushort* __restrict__ Wt, int K, int N)
{
    __shared__ ushort T[64][65];
    int n0 = blockIdx.x*64, k0 = blockIdx.y*64;
    int tid = threadIdx.x;
    #pragma unroll
    for (int p = 0; p < 4; ++p) {
        int r = p*16 + (tid>>4), c = (tid&15)<<2;
        float4 w4 = *(const float4*)(W + (size_t)(k0+r)*N + n0 + c);
        T[c+0][r] = f2bf(w4.x); T[c+1][r] = f2bf(w4.y);
        T[c+2][r] = f2bf(w4.z); T[c+3][r] = f2bf(w4.w);
    }
    __syncthreads();
    #pragma unroll
    for (int p = 0; p < 4; ++p) {
        int n = p*16 + (tid>>4), k = (tid&15)<<2;
        ushort4 o; o.x = T[n][k]; o.y = T[n][k+1]; o.z = T[n][k+2]; o.w = T[n][k+3];
        *(ushort4*)(Wt + (size_t)(n0+n)*K + k0 + k) = o;
    }
}

// 4x 512x512 weights in one launch (z selects)
__global__ __launch_bounds__(256) void wtrans4_kernel(
        const float* __restrict__ W0, const float* __restrict__ W1,
        const float* __restrict__ W2, const float* __restrict__ W3,
        ushort* __restrict__ Wt)
{
    __shared__ ushort T[64][65];
    int z = blockIdx.z;
    const float* W = (z==0) ? W0 : (z==1) ? W1 : (z==2) ? W2 : W3;
    ushort* Wtz = Wt + (size_t)z*512*512;
    int n0 = blockIdx.x*64, k0 = blockIdx.y*64;
    int tid = threadIdx.x;
    #pragma unroll
    for (int p = 0; p < 4; ++p) {
        int r = p*16 + (tid>>4), c = (tid&15)<<2;
        float4 w4 = *(const float4*)(W + (size_t)(k0+r)*512 + n0 + c);
        T[c+0][r] = f2bf(w4.x); T[c+1][r] = f2bf(w4.y);
        T[c+2][r] = f2bf(w4.z); T[c+3][r] = f2bf(w4.w);
    }
    __syncthreads();
    #pragma unroll
    for (int p = 0; p < 4; ++p) {
        int n = p*16 + (tid>>4), k = (tid&15)<<2;
        ushort4 o; o.x = T[n][k]; o.y = T[n][k+1]; o.z = T[n][k+2]; o.w = T[n][k+3];
        *(ushort4*)(Wtz + (size_t)(n0+n)*512 + k0 + k) = o;
    }
}

// ---------------- bf16 MFMA GEMM, BN=64, BK=32, double-buffered (R11-proven) ----------------
// flags: 1=QKV-split 2=GELU 4=+resid 8=+bias 16=bf16 out
template<int BM, int NT>
__global__ __launch_bounds__(NT) void gemm_bf16_kernel(
        const ushort* __restrict__ A,
        const ushort* __restrict__ Wta, const ushort* __restrict__ Wtb, const ushort* __restrict__ Wtc,
        const float* __restrict__ bias, const float* __restrict__ resid,
        void* __restrict__ outv, int M, int Nn, int K, int flags)
{
    constexpr int AISS = (BM*4)/NT;      // A-tile DMA issues
    constexpr int BISS = 256/NT;         // B-tile DMA issues
    __shared__ ushort As[2][BM*32];
    __shared__ ushort Bs[2][64*32];
    int tid = threadIdx.x;
    int w = tid >> 6, lane = tid & 63, quad = lane >> 4, col = lane & 15;
    int row0 = blockIdx.y * BM, col0 = blockIdx.x * 64;
    int wm0 = w * 32;

    const ushort* Wt; int wcol0, ostride, obase_col;
    float qscale = 1.0f;
    float* outF = nullptr; ushort* outB = nullptr;
    if (flags & 1) {
        int sel = col0 >> 9;
        Wt = (sel == 0) ? Wta : ((sel == 1) ? Wtb : Wtc);
        wcol0 = col0 & 511; ostride = 512; obase_col = wcol0;
        outB = (ushort*)outv + (size_t)sel * ((size_t)M * 512);
        if (sel == 0) qscale = 0.125f * 1.44269504088896f;  // 1/sqrt(HD) * log2(e)
        flags |= 16;
    } else {
        Wt = Wta; wcol0 = col0; ostride = Nn; obase_col = col0;
        if (flags & 16) outB = (ushort*)outv; else outF = (float*)outv;
    }

    f32x4 acc[2][4];
    #pragma unroll
    for (int i = 0; i < 2; ++i)
        #pragma unroll
        for (int j = 0; j < 4; ++j) acc[i][j] = (f32x4){0.f,0.f,0.f,0.f};

    const ushort* Ag = A  + (size_t)(row0  + (tid >> 2))*K + ((tid & 3) << 3);
    const ushort* Bg = Wt + (size_t)(wcol0 + (tid >> 2))*K + ((tid & 3) << 3);

    auto issue = [&](ushort* Ad, ushort* Bd, int ko) {
        #pragma unroll
        for (int it = 0; it < AISS; ++it)
            gload16(Ag + ko + (size_t)(it*(NT/4))*K, Ad + it*NT*8 + tid*8);
        #pragma unroll
        for (int it = 0; it < BISS; ++it)
            gload16(Bg + ko + (size_t)(it*(NT/4))*K, Bd + it*NT*8 + tid*8);
    };
    auto compute = [&](const ushort* Ab, const ushort* Bb) {
        bf16x8 af[2], bfr[4];
        #pragma unroll
        for (int i = 0; i < 2; ++i)
            af[i] = *(const bf16x8*)(Ab + (wm0 + i*16 + col)*32 + quad*8);
        #pragma unroll
        for (int j = 0; j < 4; ++j)
            bfr[j] = *(const bf16x8*)(Bb + (j*16 + col)*32 + quad*8);
        #pragma unroll
        for (int i = 0; i < 2; ++i)
            #pragma unroll
            for (int j = 0; j < 4; ++j)
                acc[i][j] = __builtin_amdgcn_mfma_f32_16x16x32_bf16(af[i], bfr[j], acc[i][j], 0, 0, 0);
    };

    int niter = K >> 5;                 // K/32, always even here
    issue(As[0], Bs[0], 0);
    for (int i = 0; i < niter; i += 2) {
        __syncthreads();                              // publish buf0 (DMA drained)
        if (i + 1 < niter) issue(As[1], Bs[1], (i+1)*32);   // prefetch overlaps compute
        compute(As[0], Bs[0]);
        __syncthreads();                              // publish buf1
        if (i + 2 < niter) issue(As[0], Bs[0], (i+2)*32);
        compute(As[1], Bs[1]);
    }

    #pragma unroll
    for (int i = 0; i < 2; ++i) {
        #pragma unroll
        for (int r = 0; r < 4; ++r) {
            int row = row0 + wm0 + i*16 + quad*4 + r;
            #pragma unroll
            for (int j = 0; j < 4; ++j) {
                int oc = obase_col + j*16 + col;
                float o = acc[i][j][r] * qscale;
                if (flags & 8) o += bias[oc];
                if (flags & 2) o = 0.5f*o*(1.f + erff(o*0.70710678118654752f));
                if (flags & 4) o += resid[(size_t)row*ostride + oc];
                if (flags & 16) outB[(size_t)row*ostride + oc] = f2bf(o);
                else            outF[(size_t)row*ostride + oc] = o;
            }
        }
    }
}

// ---------------- V transpose with PV-operand key permutation ----------------
// korig = ((key'>>5)*2 + ((key'>>2)&1))*16 + ((key'>>3)&3)*4 + (key'&3).
__global__ __launch_bounds__(256) void vtrans_kernel(const ushort* __restrict__ v,
                                                     ushort* __restrict__ vt)
{
    int tt = blockIdx.x, bh = blockIdx.y;
    int b = bh >> 3, h = bh & 7;
    int tid = threadIdx.x;
    int d = tid >> 2, t0 = (tid & 3) << 4;
    ushort tmp[16];
    #pragma unroll
    for (int i = 0; i < 16; ++i) {
        int kp = t0 + i;
        int korig = ((kp>>5)*2 + ((kp>>2)&1))*16 + ((kp>>3)&3)*4 + (kp&3);
        tmp[i] = v[(size_t)(b*SEQ + tt*64 + korig)*DIM + h*HD + d];
    }
    unsigned u[8];
    #pragma unroll
    for (int j = 0; j < 8; ++j) u[j] = (unsigned)tmp[2*j] | ((unsigned)tmp[2*j+1] << 16);
    ushort* dst = vt + ((size_t)bh*HD + d)*SEQ + tt*64 + t0;
    *(uint4*)(dst)     = make_uint4(u[0],u[1],u[2],u[3]);
    *(uint4*)(dst + 8) = make_uint4(u[4],u[5],u[6],u[7]);
}

// ---------------- MFMA flash attention: S^T/O^T, P-in-registers, dbuf K/V ----------------
// R12 structure (1 barrier/iter, register-prefetch dbuf staging) with the RNE
// pack replaced by a 1-op truncating merge (P-only: <=2^-8 rel err, safe
// within the 3.7x absmax margin). P never touches LDS.
__global__ __launch_bounds__(256) void attn_mfma_kernel(
        const ushort* __restrict__ q, const ushort* __restrict__ k,
        const ushort* __restrict__ vt, ushort* __restrict__ out)
{
    __shared__ ushort Kt[2][64][72];
    __shared__ ushort Vt[2][64][72];

    int qt = blockIdx.x, bh = blockIdx.y;
    int b = bh >> 3, h = bh & 7;
    int tid = threadIdx.x;
    int w = tid >> 6, lane = tid & 63;
    int quad = lane >> 4, col = lane & 15;
    int qn0 = qt*128 + w*32;

    bf16x8 aq[2][2];    // Q^T B-operand, resident
    #pragma unroll
    for (int mt = 0; mt < 2; ++mt) {
        const ushort* qp = q + (size_t)(b*SEQ + qn0 + mt*16 + col)*DIM + h*HD + quad*8;
        aq[mt][0] = *(const bf16x8*)(qp);
        aq[mt][1] = *(const bf16x8*)(qp + 32);
    }
    const short one_bf = (short)0x3F80;
    const bf16x8 ones = {one_bf,one_bf,one_bf,one_bf,one_bf,one_bf,one_bf,one_bf};

    f32x4 ot[2][4];
    f32x4 ol[2];
    #pragma unroll
    for (int mt = 0; mt < 2; ++mt) {
        ol[mt] = (f32x4){0.f,0.f,0.f,0.f};
        #pragma unroll
        for (int t4 = 0; t4 < 4; ++t4) ot[mt][t4] = (f32x4){0.f,0.f,0.f,0.f};
    }

    int skey = tid >> 2, sd0 = (tid & 3) << 4;
    bf16x8 kr[2], vr[2];
    auto load_tile = [&](int t) {
        const ushort* kp = k + (size_t)(b*SEQ + t*64 + skey)*DIM + h*HD + sd0;
        kr[0] = *(const bf16x8*)(kp);
        kr[1] = *(const bf16x8*)(kp + 8);
        const ushort* vp = vt + ((size_t)bh*HD + skey)*SEQ + t*64 + sd0;
        vr[0] = *(const bf16x8*)(vp);
        vr[1] = *(const bf16x8*)(vp + 8);
    };
    auto store_tile = [&](int p) {
        *(bf16x8*)&Kt[p][skey][sd0]     = kr[0];
        *(bf16x8*)&Kt[p][skey][sd0+8]   = kr[1];
        *(bf16x8*)&Vt[p][skey][sd0]     = vr[0];
        *(bf16x8*)&Vt[p][skey][sd0+8]   = vr[1];
    };

    load_tile(0);
    store_tile(0);
    __syncthreads();

    for (int t = 0; t < SEQ/64; ++t) {
        int p = t & 1;
        if (t + 1 < SEQ/64) load_tile(t + 1);     // VMEM in flight over compute

        // S^T = K Q^T
        f32x4 sc[2][4];
        #pragma unroll
        for (int mt = 0; mt < 2; ++mt)
            #pragma unroll
            for (int t4 = 0; t4 < 4; ++t4) sc[mt][t4] = (f32x4){0.f,0.f,0.f,0.f};
        #pragma unroll
        for (int c = 0; c < 2; ++c) {
            bf16x8 kf[4];
            #pragma unroll
            for (int t4 = 0; t4 < 4; ++t4)
                kf[t4] = *(const bf16x8*)&Kt[p][t4*16 + col][c*32 + quad*8];
            #pragma unroll
            for (int mt = 0; mt < 2; ++mt)
                #pragma unroll
                for (int t4 = 0; t4 < 4; ++t4)
                    sc[mt][t4] = __builtin_amdgcn_mfma_f32_16x16x32_bf16(kf[t4], aq[mt][c], sc[mt][t4], 0, 0, 0);
        }

        // P^T = exp2(S^T), in-register repack (truncating, 1 op per pair)
        union PU { bf16x8 v; uint4 u; };
        PU pb[2][2];
        #pragma unroll
        for (int mt = 0; mt < 2; ++mt)
            #pragma unroll
            for (int c = 0; c < 2; ++c) {
                pb[mt][c].u.x = pack2bf_tr(EXP2(sc[mt][2*c  ][0]), EXP2(sc[mt][2*c  ][1]));
                pb[mt][c].u.y = pack2bf_tr(EXP2(sc[mt][2*c  ][2]), EXP2(sc[mt][2*c  ][3]));
                pb[mt][c].u.z = pack2bf_tr(EXP2(sc[mt][2*c+1][0]), EXP2(sc[mt][2*c+1][1]));
                pb[mt][c].u.w = pack2bf_tr(EXP2(sc[mt][2*c+1][2]), EXP2(sc[mt][2*c+1][3]));
            }

        // O^T += V^T P^T ; l += 1 P^T
        #pragma unroll
        for (int c = 0; c < 2; ++c) {
            bf16x8 vf[4];
            #pragma unroll
            for (int t4 = 0; t4 < 4; ++t4)
                vf[t4] = *(const bf16x8*)&Vt[p][t4*16 + col][c*32 + quad*8];
            #pragma unroll
            for (int mt = 0; mt < 2; ++mt) {
                #pragma unroll
                for (int t4 = 0; t4 < 4; ++t4)
                    ot[mt][t4] = __builtin_amdgcn_mfma_f32_16x16x32_bf16(vf[t4], pb[mt][c].v, ot[mt][t4], 0, 0, 0);
                ol[mt] = __builtin_amdgcn_mfma_f32_16x16x32_bf16(ones, pb[mt][c].v, ol[mt], 0, 0, 0);
            }
        }

        if (t + 1 < SEQ/64) store_tile(p ^ 1);    // tile t-1 fully consumed pre-barrier
        __syncthreads();
    }

    #pragma unroll
    for (int mt = 0; mt < 2; ++mt) {
        float inv = 1.0f / ol[mt][0];
        #pragma unroll
        for (int t4 = 0; t4 < 4; ++t4) {
            ushort4 o4;
            o4.x = f2bf(ot[mt][t4][0] * inv);
            o4.y = f2bf(ot[mt][t4][1] * inv);
            o4.z = f2bf(ot[mt][t4][2] * inv);
            o4.w = f2bf(ot[mt][t4][3] * inv);
            *(ushort4*)(out + (size_t)(b*SEQ + qn0 + mt*16 + col)*DIM + h*HD + t4*16 + quad*4) = o4;
        }
    }
}

extern "C" void kernel_launch(void* const* d_in, const int* in_sizes, int n_in,
                              void* d_out, int out_size, void* d_ws, size_t ws_size,
                              hipStream_t stream)
{
    (void)in_sizes; (void)n_in; (void)out_size; (void)ws_size;
    const float* x   = (const float*)d_in[0];
    const float* Wq  = (const float*)d_in[1];
    const float* Wk  = (const float*)d_in[2];
    const float* Wv  = (const float*)d_in[3];
    const float* Wo  = (const float*)d_in[4];
    const float* bo  = (const float*)d_in[5];
    const float* W1  = (const float*)d_in[6];
    const float* b1  = (const float*)d_in[7];
    const float* W2  = (const float*)d_in[8];
    const float* b2  = (const float*)d_in[9];
    const float* g1  = (const float*)d_in[10];
    const float* be1 = (const float*)d_in[11];
    const float* g2  = (const float*)d_in[12];
    const float* be2 = (const float*)d_in[13];

    // workspace layout (ushort units)
    ushort* u = (ushort*)d_ws;
    float*  x2    = (float*)u;                       // [0, 2SZ) ushorts = SZ floats
    ushort* h     = u + 2*(size_t)SZ;                // [2SZ, 3SZ)
    ushort* qb    = u + 3*(size_t)SZ;                // [3SZ, 4SZ)
    ushort* kb    = u + 4*(size_t)SZ;
    ushort* vb    = u + 5*(size_t)SZ;
    ushort* vtb   = u + 6*(size_t)SZ;
    ushort* attnb = u + 7*(size_t)SZ;                // [7SZ, 8SZ)
    ushort* ff1   = u + 3*(size_t)SZ;                // overlays qb..vtb (dead by then), 4SZ
    ushort* wqkv  = u + 8*(size_t)SZ;                // 4x 512*512 (q,k,v,o)
    ushort* wto   = wqkv + 3*(size_t)512*512;
    ushort* wt1   = wqkv + 4*(size_t)512*512;        // [2048][512]
    ushort* wt2   = wt1  + (size_t)512*2048;         // [512][2048]
    float*  outp  = (float*)d_out;

    // weights -> bf16 transposed [N][K]
    wtrans4_kernel<<<dim3(8,8,4), 256, 0, stream>>>(Wq, Wk, Wv, Wo, wqkv);
    wtrans_kernel<<<dim3(32,8), 256, 0, stream>>>(W1, wt1, 512, 2048);
    wtrans_kernel<<<dim3(8,32), 256, 0, stream>>>(W2, wt2, 2048, 512);

    // h = LN(x) -> bf16
    ln_kernel<<<ROWS, 128, 0, stream>>>(x, g1, be1, h);
    // q,k,v = h @ {Wq,Wk,Wv} -> bf16 (q scaled by 0.125*log2e)  [R11 config]
    gemm_bf16_kernel<128,256><<<dim3(1536/64, ROWS/128), 256, 0, stream>>>(
        h, wqkv, wqkv + (size_t)512*512, wqkv + 2*(size_t)512*512,
        nullptr, nullptr, qb, ROWS, 1536, DIM, 1);
    // vt = permuted transpose(v)
    vtrans_kernel<<<dim3(SEQ/64, BB*NH), 256, 0, stream>>>(vb, vtb);
    // attn = flash(q,k,v) -> bf16
    attn_mfma_kernel<<<dim3(SEQ/128, BB*NH), 256, 0, stream>>>(qb, kb, vtb, attnb);
    // x2 = x + attn @ Wo + bo  (fp32)
    gemm_bf16_kernel<64,128><<<dim3(DIM/64, ROWS/64), 128, 0, stream>>>(
        attnb, wto, wto, wto, bo, x, x2, ROWS, DIM, DIM, 8|4);
    // h = LN(x2) -> bf16
    ln_kernel<<<ROWS, 128, 0, stream>>>(x2, g2, be2, h);
    // ff1 = gelu(h @ W1 + b1) -> bf16  [R11 config]
    gemm_bf16_kernel<128,256><<<dim3(MLPD/64, ROWS/128), 256, 0, stream>>>(
        h, wt1, wt1, wt1, b1, nullptr, ff1, ROWS, MLPD, DIM, 8|2|16);
    // out = x2 + ff1 @ W2 + b2  (fp32)
    gemm_bf16_kernel<64,128><<<dim3(DIM/64, ROWS/64), 128, 0, stream>>>(
        ff1, wt2, wt2, wt2, b2, x2, outp, ROWS, DIM, MLPD, 8|4);
}